// Round 1
// baseline (1829.972 us; speedup 1.0000x reference)
//
#include <hip/hip_runtime.h>
#include <hip/hip_bf16.h>

#define Bsz 256
#define Tsz 2048
#define Fsz 128
#define Hsz 32

typedef __attribute__((ext_vector_type(4))) float f32x4;
typedef __attribute__((ext_vector_type(8))) short bf16x8;

__device__ __forceinline__ unsigned short f2b(float f){
  union { __hip_bfloat16 h; unsigned short u; } cv;
  cv.h = __float2bfloat16(f);
  return cv.u;
}

// ---- prep: Wt[g][k] = bf16(W[k][g])  (B-operand wants K-contiguous per column) ----
__global__ __launch_bounds__(256) void prep_wt(const float* __restrict__ W,
                                               unsigned short* __restrict__ Wt){
  int i = blockIdx.x*256 + threadIdx.x;   // 0..16383
  int k = i >> 7, g = i & 127;
  Wt[g*128 + k] = f2b(W[k*128 + g]);
}

// ---- GEMM: xz[bb][t0+tt*128+r][g] = x[bb][t0+tt*128+r][:] @ W + bias ----
// 128x128 output tile per block (K=128 whole), 4 waves in 2x2, bf16 MFMA.
__global__ __launch_bounds__(256) void gemm_xw(
    const float* __restrict__ x,
    const unsigned short* __restrict__ Wt,  // [128][128] bf16, (g,k)
    const float* __restrict__ bias,
    float* __restrict__ xz,                 // chunk [256][Tc][128] fp32
    int t0, int Tc)
{
  __shared__ unsigned short Asl[128*128];   // [row][k] bf16, XOR-swizzled
  __shared__ unsigned short Bsl[128*128];   // [col][k] bf16, XOR-swizzled
  int tid = threadIdx.x;
  int tpb = Tc >> 7;
  int bb = blockIdx.x / tpb;
  int tt = blockIdx.x - bb*tpb;

  // stage A: 128 rows x 128 k, fp32 -> bf16, swizzle byte ^= (row&7)<<4
  const float4* xg = (const float4*)(x + ((size_t)bb*Tsz + (size_t)t0 + (size_t)tt*128)*128);
  #pragma unroll
  for (int it = 0; it < 16; ++it){
    int idx = it*256 + tid;               // float4 index; element e = idx*4
    float4 v = xg[idx];
    ushort4 u; u.x=f2b(v.x); u.y=f2b(v.y); u.z=f2b(v.z); u.w=f2b(v.w);
    int row  = idx >> 5;                  // e>>7
    int byte = (idx << 3) ^ ((row & 7) << 4);
    *(ushort4*)((char*)Asl + byte) = u;
  }
  // stage B: already bf16, 2048 x 16B granules, same swizzle (col = granule>>4)
  const int4* wg = (const int4*)Wt;
  #pragma unroll
  for (int it = 0; it < 8; ++it){
    int idx = it*256 + tid;
    int col = idx >> 4;
    int byte = (idx << 4) ^ ((col & 7) << 4);
    *(int4*)((char*)Bsl + byte) = wg[idx];
  }
  __syncthreads();

  int w = tid >> 6, l = tid & 63;
  int wm = w >> 1, wn = w & 1;            // 2x2 wave grid, 64x64 per wave
  int lr = l & 15, lk = l >> 4;
  f32x4 acc[4][4] = {};

  #pragma unroll
  for (int kk = 0; kk < 128; kk += 32){
    bf16x8 af[4], bfr[4];
    #pragma unroll
    for (int m = 0; m < 4; ++m){
      int row  = wm*64 + m*16 + lr;
      int byte = (row*256 + (kk + lk*8)*2) ^ ((row & 7) << 4);
      af[m] = *(const bf16x8*)((const char*)Asl + byte);
    }
    #pragma unroll
    for (int n = 0; n < 4; ++n){
      int col  = wn*64 + n*16 + lr;
      int byte = (col*256 + (kk + lk*8)*2) ^ ((col & 7) << 4);
      bfr[n] = *(const bf16x8*)((const char*)Bsl + byte);
    }
    #pragma unroll
    for (int m = 0; m < 4; ++m)
      #pragma unroll
      for (int n = 0; n < 4; ++n)
        acc[m][n] = __builtin_amdgcn_mfma_f32_16x16x32_bf16(af[m], bfr[n], acc[m][n], 0, 0, 0);
  }

  // epilogue: D row=(lane>>4)*4+r, col=lane&15 (guide m89-verified mapping)
  float* outp = xz + ((size_t)bb*Tc + (size_t)tt*128)*128;
  #pragma unroll
  for (int m = 0; m < 4; ++m){
    int row0 = wm*64 + m*16 + lk*4;
    #pragma unroll
    for (int n = 0; n < 4; ++n){
      int col = wn*64 + n*16 + lr;
      float bs = bias[col];
      #pragma unroll
      for (int r = 0; r < 4; ++r)
        outp[(size_t)(row0 + r)*128 + col] = acc[m][n][r] + bs;
    }
  }
}

// ---- scan: one block (128 thr, 2 waves) per batch row; thread g owns z-col g ----
__device__ __forceinline__ float sigm(float x){ return 1.f/(1.f + __expf(-x)); }
__device__ __forceinline__ float tanh_fast(float x){ return 1.f - 2.f/(1.f + __expf(2.f*x)); }

__global__ __launch_bounds__(128) void lstm_scan(
    const float* __restrict__ xz,   // chunk [256][Tc][128]
    const float* __restrict__ U,    // [32][128]
    float* __restrict__ hst, float* __restrict__ cst,  // [256][32] state in ws
    float* __restrict__ out, int Tc, int first, int last)
{
  int b = blockIdx.x, g = threadIdx.x;
  float Ur[32];
  #pragma unroll
  for (int j = 0; j < 32; ++j) Ur[j] = U[j*128 + g];

  __shared__ float h_s[32];
  __shared__ float a_s[128];
  float c = 0.f;
  if (g < 32){
    float h0 = 0.f;
    if (!first){ h0 = hst[b*32 + g]; c = cst[b*32 + g]; }
    h_s[g] = h0;
  }
  __syncthreads();

  const float* xp = xz + (size_t)b*Tc*128 + g;
  float v0 = xp[0];
  float v1 = xp[128];
  for (int t = 0; t < Tc; ++t){
    float acc = v0;                        // xz already includes bias
    v0 = v1;
    if (t + 2 < Tc) v1 = xp[(size_t)(t + 2)*128];
    #pragma unroll
    for (int j = 0; j < 32; ++j) acc = fmaf(h_s[j], Ur[j], acc);
    // gate order i,f,g,o: cols [0,32) sig, [32,64) sig, [64,96) tanh, [96,128) sig
    float a = (g >= 64 && g < 96) ? tanh_fast(acc) : sigm(acc);
    a_s[g] = a;
    __syncthreads();
    if (g < 32){
      c = fmaf(a_s[g + 32], c, a_s[g] * a_s[g + 64]);
      h_s[g] = a_s[g + 96] * tanh_fast(c);
    }
    __syncthreads();
  }
  if (g < 32){
    hst[b*32 + g] = h_s[g];
    cst[b*32 + g] = c;
    if (last) out[b*32 + g] = h_s[g];
  }
}

extern "C" void kernel_launch(void* const* d_in, const int* in_sizes, int n_in,
                              void* d_out, int out_size, void* d_ws, size_t ws_size,
                              hipStream_t stream)
{
  (void)in_sizes; (void)n_in; (void)out_size;
  const float* x    = (const float*)d_in[0];   // [256][2048][128]
  const float* W    = (const float*)d_in[1];   // [128][128]
  const float* U    = (const float*)d_in[2];   // [32][128]
  const float* bias = (const float*)d_in[3];   // [128]
  float* out = (float*)d_out;                  // [256][32]

  char* wsb = (char*)d_ws;
  unsigned short* Wt = (unsigned short*)wsb;        // 32 KB
  float* hst = (float*)(wsb + 32768);               // 32 KB
  float* cst = (float*)(wsb + 65536);               // 32 KB
  float* xzb = (float*)(wsb + 98304);               // chunk buffer

  // pick largest power-of-two chunk that fits in ws (deterministic per session)
  size_t avail = ws_size > 98304 ? ws_size - 98304 : 0;
  int Tc = 2048;
  while (Tc > 128 && (size_t)Tc*131072ull > avail) Tc >>= 1;

  hipLaunchKernelGGL(prep_wt, dim3(64), dim3(256), 0, stream, W, Wt);
  int nch = Tsz / Tc;
  for (int ch = 0; ch < nch; ++ch){
    hipLaunchKernelGGL(gemm_xw, dim3(256*(Tc >> 7)), dim3(256), 0, stream,
                       x, Wt, bias, xzb, ch*Tc, Tc);
    hipLaunchKernelGGL(lstm_scan, dim3(256), dim3(128), 0, stream,
                       xzb, U, hst, cst, out, Tc, ch == 0 ? 1 : 0, ch == nch-1 ? 1 : 0);
  }
}

// Round 4
// 1167.430 us; speedup vs baseline: 1.5675x; 1.5675x over previous
//
#include <hip/hip_runtime.h>
#include <hip/hip_bf16.h>

#define Bsz 256
#define Tsz 2048
#define Fsz 128
#define Hsz 32

typedef __attribute__((ext_vector_type(4))) float f32x4;
typedef __attribute__((ext_vector_type(2))) float f32x2;
typedef __attribute__((ext_vector_type(8))) short bf16x8;

__device__ __forceinline__ unsigned short f2b(float f){
  union { __hip_bfloat16 h; unsigned short u; } cv;
  cv.h = __float2bfloat16(f);
  return cv.u;
}

// ---- prep: Wt[g][k] = bf16(W[k][g]) ----
__global__ __launch_bounds__(256) void prep_wt(const float* __restrict__ W,
                                               unsigned short* __restrict__ Wt){
  int i = blockIdx.x*256 + threadIdx.x;   // 0..16383
  int k = i >> 7, g = i & 127;
  Wt[g*128 + k] = f2b(W[k*128 + g]);
}

// ---- GEMM: xz = x @ W + b  (128x128 tile/block, bf16 MFMA, fp32 out) ----
__global__ __launch_bounds__(256) void gemm_xw(
    const float* __restrict__ x,
    const unsigned short* __restrict__ Wt,  // [128][128] bf16, (g,k)
    const float* __restrict__ bias,
    float* __restrict__ xz,                 // chunk [256][Tc][128] fp32
    int t0, int Tc)
{
  __shared__ unsigned short Asl[128*128];
  __shared__ unsigned short Bsl[128*128];
  int tid = threadIdx.x;
  int tpb = Tc >> 7;
  int bb = blockIdx.x / tpb;
  int tt = blockIdx.x - bb*tpb;

  const float4* xg = (const float4*)(x + ((size_t)bb*Tsz + (size_t)t0 + (size_t)tt*128)*128);
  #pragma unroll
  for (int it = 0; it < 16; ++it){
    int idx = it*256 + tid;
    float4 v = xg[idx];
    ushort4 u; u.x=f2b(v.x); u.y=f2b(v.y); u.z=f2b(v.z); u.w=f2b(v.w);
    int row  = idx >> 5;
    int byte = (idx << 3) ^ ((row & 7) << 4);
    *(ushort4*)((char*)Asl + byte) = u;
  }
  const int4* wg = (const int4*)Wt;
  #pragma unroll
  for (int it = 0; it < 8; ++it){
    int idx = it*256 + tid;
    int col = idx >> 4;
    int byte = (idx << 4) ^ ((col & 7) << 4);
    *(int4*)((char*)Bsl + byte) = wg[idx];
  }
  __syncthreads();

  int w = tid >> 6, l = tid & 63;
  int wm = w >> 1, wn = w & 1;
  int lr = l & 15, lk = l >> 4;
  f32x4 acc[4][4] = {};

  #pragma unroll
  for (int kk = 0; kk < 128; kk += 32){
    bf16x8 af[4], bfr[4];
    #pragma unroll
    for (int m = 0; m < 4; ++m){
      int row  = wm*64 + m*16 + lr;
      int byte = (row*256 + (kk + lk*8)*2) ^ ((row & 7) << 4);
      af[m] = *(const bf16x8*)((const char*)Asl + byte);
    }
    #pragma unroll
    for (int n = 0; n < 4; ++n){
      int col  = wn*64 + n*16 + lr;
      int byte = (col*256 + (kk + lk*8)*2) ^ ((col & 7) << 4);
      bfr[n] = *(const bf16x8*)((const char*)Bsl + byte);
    }
    #pragma unroll
    for (int m = 0; m < 4; ++m)
      #pragma unroll
      for (int n = 0; n < 4; ++n)
        acc[m][n] = __builtin_amdgcn_mfma_f32_16x16x32_bf16(af[m], bfr[n], acc[m][n], 0, 0, 0);
  }

  float* outp = xz + ((size_t)bb*Tc + (size_t)tt*128)*128;
  #pragma unroll
  for (int m = 0; m < 4; ++m){
    int row0 = wm*64 + m*16 + lk*4;
    #pragma unroll
    for (int n = 0; n < 4; ++n){
      int col = wn*64 + n*16 + lr;
      float bs = bias[col];
      #pragma unroll
      for (int r = 0; r < 4; ++r)
        outp[(size_t)(row0 + r)*128 + col] = acc[m][n][r] + bs;
    }
  }
}

// ---- scan: one 64-lane wave per batch row; lane l owns cols l and l+64 ----
__device__ __forceinline__ float sigm_fast(float x){
  return __builtin_amdgcn_rcpf(1.f + __expf(-x));
}

__global__ __launch_bounds__(64) void lstm_scan(
    const float* __restrict__ xz,   // chunk [256][Tc][128]
    const float* __restrict__ U,    // [32][128]
    float* __restrict__ hst, float* __restrict__ cst,  // [256][32]
    float* __restrict__ out, int Tc, int first, int last)
{
  int b = blockIdx.x, l = threadIdx.x;
  int half = l >> 5;                 // 0: (i,g) cols; 1: (f,o) cols

  // packed recurrent weights for cols l and l+64
  f32x2 Upk[32];
  #pragma unroll
  for (int j = 0; j < 32; ++j)
    Upk[j] = (f32x2){ U[j*128 + l], U[j*128 + l + 64] };

  __shared__ __align__(16) float h_s[64];
  float c = 0.f;
  {
    int u = l & 31;
    float h0 = 0.f;
    if (!first){ h0 = hst[b*32 + u]; c = cst[b*32 + u]; }
    h_s[l] = h0;                     // lanes 32..63 write redundant copy at [32+u]
  }
  __syncthreads();

  const float* xp = xz + (size_t)b*Tc*128 + l;
  #define LDX(T) ((f32x2){ xp[(size_t)(T)*128], xp[(size_t)(T)*128 + 64] })
  f32x2 xv0 = LDX(0), xv1 = LDX(1), xv2 = LDX(2), xv3 = LDX(3);

  const float4* h4 = (const float4*)h_s;

  #define STEP(XV, TT) {                                                      \
    f32x2 cur = (XV);                                                         \
    if ((TT) + 4 < Tc) (XV) = LDX((TT) + 4);    /* prefetch 4 ahead */        \
    f32x2 A0 = cur, A1 = (f32x2)(0.f), A2 = (f32x2)(0.f), A3 = (f32x2)(0.f);  \
    _Pragma("unroll")                                                         \
    for (int k = 0; k < 8; ++k){                                              \
      float4 hv = h4[k];                                                      \
      A0 = __builtin_elementwise_fma((f32x2){hv.x, hv.x}, Upk[4*k+0], A0);    \
      A1 = __builtin_elementwise_fma((f32x2){hv.y, hv.y}, Upk[4*k+1], A1);    \
      A2 = __builtin_elementwise_fma((f32x2){hv.z, hv.z}, Upk[4*k+2], A2);    \
      A3 = __builtin_elementwise_fma((f32x2){hv.w, hv.w}, Upk[4*k+3], A3);    \
    }                                                                         \
    f32x2 z = (A0 + A1) + (A2 + A3);                                          \
    float a0 = sigm_fast(z.x);                  /* i (half0) or f (half1) */  \
    float zs = half ? z.y : 2.f * z.y;                                        \
    float s1 = sigm_fast(zs);                                                 \
    float a1 = half ? s1 : fmaf(2.f, s1, -1.f); /* g=tanh (half0), o (half1)*/\
    auto r0 = __builtin_amdgcn_permlane32_swap(__float_as_int(a0),            \
                                               __float_as_int(a0), false, false); \
    auto r1 = __builtin_amdgcn_permlane32_swap(__float_as_int(a1),            \
                                               __float_as_int(a1), false, false); \
    float p0 = __int_as_float(half ? r0[0] : r0[1]);                          \
    float p1 = __int_as_float(half ? r1[0] : r1[1]);                          \
    float i_ = half ? p0 : a0;                                                \
    float g_ = half ? p1 : a1;                                                \
    float f_ = half ? a0 : p0;                                                \
    float o_ = half ? a1 : p1;                                                \
    c = fmaf(f_, c, i_ * g_);                                                 \
    float e2 = __expf(-2.f * c);                                              \
    float th = fmaf(2.f, __builtin_amdgcn_rcpf(1.f + e2), -1.f);              \
    float hh = o_ * th;                                                       \
    h_s[l] = hh;                                                              \
    __syncthreads();                                                          \
  }

  for (int t = 0; t < Tc; t += 4){
    STEP(xv0, t + 0)
    STEP(xv1, t + 1)
    STEP(xv2, t + 2)
    STEP(xv3, t + 3)
  }
  #undef STEP
  #undef LDX

  if (l < 32){
    hst[b*32 + l] = h_s[l];
    cst[b*32 + l] = c;
    if (last) out[b*32 + l] = h_s[l];
  }
}

extern "C" void kernel_launch(void* const* d_in, const int* in_sizes, int n_in,
                              void* d_out, int out_size, void* d_ws, size_t ws_size,
                              hipStream_t stream)
{
  (void)in_sizes; (void)n_in; (void)out_size;
  const float* x    = (const float*)d_in[0];   // [256][2048][128]
  const float* W    = (const float*)d_in[1];   // [128][128]
  const float* U    = (const float*)d_in[2];   // [32][128]
  const float* bias = (const float*)d_in[3];   // [128]
  float* out = (float*)d_out;                  // [256][32]

  char* wsb = (char*)d_ws;
  unsigned short* Wt = (unsigned short*)wsb;        // 32 KB
  float* hst = (float*)(wsb + 32768);               // 32 KB
  float* cst = (float*)(wsb + 65536);               // 32 KB
  float* xzb = (float*)(wsb + 98304);               // chunk buffer

  size_t avail = ws_size > 98304 ? ws_size - 98304 : 0;
  int Tc = 2048;
  while (Tc > 128 && (size_t)Tc*131072ull > avail) Tc >>= 1;

  hipLaunchKernelGGL(prep_wt, dim3(64), dim3(256), 0, stream, W, Wt);
  int nch = Tsz / Tc;
  for (int ch = 0; ch < nch; ++ch){
    hipLaunchKernelGGL(gemm_xw, dim3(256*(Tc >> 7)), dim3(256), 0, stream,
                       x, Wt, bias, xzb, ch*Tc, Tc);
    hipLaunchKernelGGL(lstm_scan, dim3(256), dim3(64), 0, stream,
                       xzb, U, hst, cst, out, Tc, ch == 0 ? 1 : 0, ch == nch-1 ? 1 : 0);
  }
}

// Round 5
// 896.242 us; speedup vs baseline: 2.0418x; 1.3026x over previous
//
#include <hip/hip_runtime.h>
#include <hip/hip_bf16.h>

#define Bsz 256
#define Tsz 2048
#define Fsz 128
#define Hsz 32

typedef __attribute__((ext_vector_type(4))) float f32x4;
typedef __attribute__((ext_vector_type(2))) float f32x2;
typedef __attribute__((ext_vector_type(8))) short bf16x8;

__device__ __forceinline__ unsigned short f2b(float f){
  union { __hip_bfloat16 h; unsigned short u; } cv;
  cv.h = __float2bfloat16(f);
  return cv.u;
}

// ---- prep: Wt[g][k] = bf16(W[k][g]) ----
__global__ __launch_bounds__(256) void prep_wt(const float* __restrict__ W,
                                               unsigned short* __restrict__ Wt){
  int i = blockIdx.x*256 + threadIdx.x;   // 0..16383
  int k = i >> 7, g = i & 127;
  Wt[g*128 + k] = f2b(W[k*128 + g]);
}

// ---- GEMM: xz = x @ W + b  (128x128 tile/block, bf16 MFMA, fp32 out) ----
__global__ __launch_bounds__(256) void gemm_xw(
    const float* __restrict__ x,
    const unsigned short* __restrict__ Wt,  // [128][128] bf16, (g,k)
    const float* __restrict__ bias,
    float* __restrict__ xz,                 // chunk [256][Tc][128] fp32
    int t0, int Tc)
{
  __shared__ unsigned short Asl[128*128];
  __shared__ unsigned short Bsl[128*128];
  int tid = threadIdx.x;
  int tpb = Tc >> 7;
  int bb = blockIdx.x / tpb;
  int tt = blockIdx.x - bb*tpb;

  const float4* xg = (const float4*)(x + ((size_t)bb*Tsz + (size_t)t0 + (size_t)tt*128)*128);
  #pragma unroll
  for (int it = 0; it < 16; ++it){
    int idx = it*256 + tid;
    float4 v = xg[idx];
    ushort4 u; u.x=f2b(v.x); u.y=f2b(v.y); u.z=f2b(v.z); u.w=f2b(v.w);
    int row  = idx >> 5;
    int byte = (idx << 3) ^ ((row & 7) << 4);
    *(ushort4*)((char*)Asl + byte) = u;
  }
  const int4* wg = (const int4*)Wt;
  #pragma unroll
  for (int it = 0; it < 8; ++it){
    int idx = it*256 + tid;
    int col = idx >> 4;
    int byte = (idx << 4) ^ ((col & 7) << 4);
    *(int4*)((char*)Bsl + byte) = wg[idx];
  }
  __syncthreads();

  int w = tid >> 6, l = tid & 63;
  int wm = w >> 1, wn = w & 1;
  int lr = l & 15, lk = l >> 4;
  f32x4 acc[4][4] = {};

  #pragma unroll
  for (int kk = 0; kk < 128; kk += 32){
    bf16x8 af[4], bfr[4];
    #pragma unroll
    for (int m = 0; m < 4; ++m){
      int row  = wm*64 + m*16 + lr;
      int byte = (row*256 + (kk + lk*8)*2) ^ ((row & 7) << 4);
      af[m] = *(const bf16x8*)((const char*)Asl + byte);
    }
    #pragma unroll
    for (int n = 0; n < 4; ++n){
      int col  = wn*64 + n*16 + lr;
      int byte = (col*256 + (kk + lk*8)*2) ^ ((col & 7) << 4);
      bfr[n] = *(const bf16x8*)((const char*)Bsl + byte);
    }
    #pragma unroll
    for (int m = 0; m < 4; ++m)
      #pragma unroll
      for (int n = 0; n < 4; ++n)
        acc[m][n] = __builtin_amdgcn_mfma_f32_16x16x32_bf16(af[m], bfr[n], acc[m][n], 0, 0, 0);
  }

  float* outp = xz + ((size_t)bb*Tc + (size_t)tt*128)*128;
  #pragma unroll
  for (int m = 0; m < 4; ++m){
    int row0 = wm*64 + m*16 + lk*4;
    #pragma unroll
    for (int n = 0; n < 4; ++n){
      int col = wn*64 + n*16 + lr;
      float bs = bias[col];
      #pragma unroll
      for (int r = 0; r < 4; ++r)
        outp[(size_t)(row0 + r)*128 + col] = acc[m][n][r] + bs;
    }
  }
}

// ---- scan: one 64-lane wave per batch row; lane l owns cols l and l+64 ----
// h broadcast via v_readlane (no LDS, no barrier on the critical path).
__device__ __forceinline__ float sigm_fast(float x){
  return __builtin_amdgcn_rcpf(1.f + __expf(-x));
}
__device__ __forceinline__ float bcast_lane(float v, int lane){
  return __int_as_float(__builtin_amdgcn_readlane(__float_as_int(v), lane));
}

__global__ __launch_bounds__(64) void lstm_scan(
    const float* __restrict__ xz,   // chunk [256][Tc][128]
    const float* __restrict__ U,    // [32][128]
    float* __restrict__ hst, float* __restrict__ cst,  // [256][32]
    float* __restrict__ out, int Tc, int first, int last)
{
  int b = blockIdx.x, l = threadIdx.x;
  int half = l >> 5;                 // 0: (i,g) cols; 1: (f,o) cols
  int u = l & 31;

  // packed recurrent weights for cols l and l+64
  f32x2 Upk[32];
  #pragma unroll
  for (int j = 0; j < 32; ++j)
    Upk[j] = (f32x2){ U[j*128 + l], U[j*128 + l + 64] };

  // state: lane u and lane u+32 both hold h[u], c[u]
  float c = 0.f, h = 0.f;
  if (!first){ h = hst[b*32 + u]; c = cst[b*32 + u]; }

  const float* xp = xz + (size_t)b*Tc*128 + l;
  #define LDX(T) ((f32x2){ xp[(size_t)(T)*128], xp[(size_t)(T)*128 + 64] })
  f32x2 xv0 = LDX(0), xv1 = LDX(1), xv2 = LDX(2), xv3 = LDX(3);
  f32x2 xv4 = LDX(4), xv5 = LDX(5), xv6 = LDX(6), xv7 = LDX(7);

  #define STEP(XV, TT) {                                                      \
    f32x2 cur = (XV);                                                         \
    if ((TT) + 8 < Tc) (XV) = LDX((TT) + 8);    /* prefetch 8 ahead */        \
    float sh[32];                                                             \
    _Pragma("unroll")                                                         \
    for (int j = 0; j < 32; ++j) sh[j] = bcast_lane(h, j);                    \
    f32x2 A0 = cur, A1 = (f32x2)(0.f), A2 = (f32x2)(0.f), A3 = (f32x2)(0.f);  \
    _Pragma("unroll")                                                         \
    for (int k = 0; k < 8; ++k){                                              \
      A0 = __builtin_elementwise_fma((f32x2){sh[4*k+0], sh[4*k+0]}, Upk[4*k+0], A0); \
      A1 = __builtin_elementwise_fma((f32x2){sh[4*k+1], sh[4*k+1]}, Upk[4*k+1], A1); \
      A2 = __builtin_elementwise_fma((f32x2){sh[4*k+2], sh[4*k+2]}, Upk[4*k+2], A2); \
      A3 = __builtin_elementwise_fma((f32x2){sh[4*k+3], sh[4*k+3]}, Upk[4*k+3], A3); \
    }                                                                         \
    f32x2 z = (A0 + A1) + (A2 + A3);                                          \
    float a0 = sigm_fast(z.x);                  /* i (half0) or f (half1) */  \
    float zs = half ? z.y : 2.f * z.y;                                        \
    float s1 = sigm_fast(zs);                                                 \
    float a1 = half ? s1 : fmaf(2.f, s1, -1.f); /* g=tanh (half0), o (half1)*/\
    auto r0 = __builtin_amdgcn_permlane32_swap(__float_as_int(a0),            \
                                               __float_as_int(a0), false, false); \
    auto r1 = __builtin_amdgcn_permlane32_swap(__float_as_int(a1),            \
                                               __float_as_int(a1), false, false); \
    float p0 = __int_as_float(half ? r0[0] : r0[1]);                          \
    float p1 = __int_as_float(half ? r1[0] : r1[1]);                          \
    float i_ = half ? p0 : a0;                                                \
    float g_ = half ? p1 : a1;                                                \
    float f_ = half ? a0 : p0;                                                \
    float o_ = half ? a1 : p1;                                                \
    c = fmaf(f_, c, i_ * g_);                                                 \
    float e2 = __expf(-2.f * c);                                              \
    float th = fmaf(2.f, __builtin_amdgcn_rcpf(1.f + e2), -1.f);              \
    h = o_ * th;                                                              \
  }

  for (int t = 0; t < Tc; t += 8){
    STEP(xv0, t + 0)
    STEP(xv1, t + 1)
    STEP(xv2, t + 2)
    STEP(xv3, t + 3)
    STEP(xv4, t + 4)
    STEP(xv5, t + 5)
    STEP(xv6, t + 6)
    STEP(xv7, t + 7)
  }
  #undef STEP
  #undef LDX

  if (l < 32){
    hst[b*32 + l] = h;
    cst[b*32 + l] = c;
    if (last) out[b*32 + l] = h;
  }
}

extern "C" void kernel_launch(void* const* d_in, const int* in_sizes, int n_in,
                              void* d_out, int out_size, void* d_ws, size_t ws_size,
                              hipStream_t stream)
{
  (void)in_sizes; (void)n_in; (void)out_size;
  const float* x    = (const float*)d_in[0];   // [256][2048][128]
  const float* W    = (const float*)d_in[1];   // [128][128]
  const float* U    = (const float*)d_in[2];   // [32][128]
  const float* bias = (const float*)d_in[3];   // [128]
  float* out = (float*)d_out;                  // [256][32]

  char* wsb = (char*)d_ws;
  unsigned short* Wt = (unsigned short*)wsb;        // 32 KB
  float* hst = (float*)(wsb + 32768);               // 32 KB
  float* cst = (float*)(wsb + 65536);               // 32 KB
  float* xzb = (float*)(wsb + 98304);               // chunk buffer

  size_t avail = ws_size > 98304 ? ws_size - 98304 : 0;
  int Tc = 2048;
  while (Tc > 128 && (size_t)Tc*131072ull > avail) Tc >>= 1;

  hipLaunchKernelGGL(prep_wt, dim3(64), dim3(256), 0, stream, W, Wt);
  int nch = Tsz / Tc;
  for (int ch = 0; ch < nch; ++ch){
    hipLaunchKernelGGL(gemm_xw, dim3(256*(Tc >> 7)), dim3(256), 0, stream,
                       x, Wt, bias, xzb, ch*Tc, Tc);
    hipLaunchKernelGGL(lstm_scan, dim3(256), dim3(64), 0, stream,
                       xzb, U, hst, cst, out, Tc, ch == 0 ? 1 : 0, ch == nch-1 ? 1 : 0);
  }
}